// Round 13
// baseline (17851.060 us; speedup 1.0000x reference)
//
#include <hip/hip_runtime.h>
#include <math.h>

#define B 64
#define T_READ 128
#define L_WRITE 32
#define TT 160
#define D 256
#define R 1024
#define N 512
#define M 128
#define HD 524
#define K5K 1152
#define EPS 1e-8f

__device__ __forceinline__ float sigmoidf(float x){ return 1.0f/(1.0f+expf(-x)); }
__device__ __forceinline__ float softplusf(float x){ return (x > 20.f) ? x : log1pf(expf(x)); }

// ---------- one-time: transpose x -> xT[t][k][b] ----------
__global__ __launch_bounds__(256) void kx_transpose(const float* __restrict__ x, float* __restrict__ xT){
    __shared__ float tile[64][65];
    const int t = blockIdx.x >> 2, k0 = (blockIdx.x & 3)*64;
    #pragma unroll
    for (int rep = 0; rep < 16; ++rep){
        int idx = rep*256 + threadIdx.x;
        int bl = idx >> 6, kl = idx & 63;
        tile[bl][kl] = x[((size_t)bl*T_READ + t)*D + k0 + kl];
    }
    __syncthreads();
    #pragma unroll
    for (int rep = 0; rep < 16; ++rep){
        int idx = rep*256 + threadIdx.x;
        int kl = idx >> 6, bl = idx & 63;
        xT[((size_t)t*D + k0 + kl)*64 + bl] = tile[bl][kl];
    }
}

// ---------- one-time: pack Wl/Ul into per-block-contiguous Wre[bk][k][16] ----------
__global__ __launch_bounds__(256) void kpack_w(const float* __restrict__ Wl, const float* __restrict__ Ul,
                                               float* __restrict__ Wre){
    const int k = blockIdx.x;                 // 0..1407
    const float* src = (k < 384) ? (Wl + (size_t)k*4096) : (Ul + (size_t)(k-384)*4096);
    #pragma unroll
    for (int it = 0; it < 16; ++it){
        int j = it*256 + threadIdx.x;         // 0..4095
        int bk = j >> 4, r = j & 15, q = r >> 2, i = r & 3;
        Wre[((size_t)bk*1408 + k)*16 + r] = src[q*1024 + bk*4 + i];
    }
}

// ---------- one-time: init state ----------
__global__ void k_init(float* ht, float* c_t, float* rp, float* wst, float* Mem){
    int idx = blockIdx.x*blockDim.x + threadIdx.x;
    int stride = gridDim.x*blockDim.x;
    for (int i = idx; i < B*N*M; i += stride) Mem[i] = 1e-6f;
    for (int i = idx; i < R*64; i += stride){ ht[i]=0.f; c_t[i]=0.f; }
    for (int i = idx; i < 4*128*64; i += stride) rp[i] = 0.f;
    for (int i = idx; i < 2*B*N; i += stride) wst[i] = 1.f/512.f;   // parity-0, both heads
}

// ---------- K1: combine reads; z = W·[x,reads] + U·h + b; LSTM gates. grid 256 x 512 ----------
__global__ __launch_bounds__(512) void k1_z(
    const float* __restrict__ xT, const float* __restrict__ Wre, const float* __restrict__ bl,
    float* __restrict__ ht, float* __restrict__ c_t, const float* __restrict__ rp,
    float* __restrict__ hist, int t)
{
    __shared__ float smem[16384];   // [0,8192) reads staging, [8192,16384) comb
    const int bk = blockIdx.x;
    const int tid = threadIdx.x, lane = tid & 63, w = tid >> 6;

    for (int e = tid; e < 8192; e += 512){
        float s = rp[e] + rp[8192+e] + rp[16384+e] + rp[24576+e];
        smem[e] = s;
        if (t > T_READ)
            __builtin_nontemporal_store(s, &hist[((size_t)(t-1-T_READ)*K5K + 1024 + (e>>6))*64 + (e&63)]);
    }
    __syncthreads();

    const int r0 = bk*4;
    const int rd = (t < T_READ);
    const int kn = rd ? 176 : 144;
    const int k0 = rd ? w*176 : 256 + w*144;
    const float* wbase = Wre + ((size_t)bk*1408 + k0)*16;
    float acc[16];
    #pragma unroll
    for (int i = 0; i < 16; ++i) acc[i] = 0.f;
    #pragma unroll 4
    for (int kk = 0; kk < kn; ++kk){
        int k = k0 + kk;
        float a;
        if (k < 256)      a = __builtin_nontemporal_load(&xT[((size_t)t*256 + k)*64 + lane]);
        else if (k < 384) a = smem[(k-256)*64 + lane];
        else              a = ht[(size_t)(k-384)*64 + lane];
        const float4* wv4 = reinterpret_cast<const float4*>(wbase + (size_t)kk*16);
        float4 w0 = wv4[0], w1 = wv4[1], w2 = wv4[2], w3 = wv4[3];
        acc[0]+=a*w0.x;  acc[1]+=a*w0.y;  acc[2]+=a*w0.z;  acc[3]+=a*w0.w;
        acc[4]+=a*w1.x;  acc[5]+=a*w1.y;  acc[6]+=a*w1.z;  acc[7]+=a*w1.w;
        acc[8]+=a*w2.x;  acc[9]+=a*w2.y;  acc[10]+=a*w2.z; acc[11]+=a*w2.w;
        acc[12]+=a*w3.x; acc[13]+=a*w3.y; acc[14]+=a*w3.z; acc[15]+=a*w3.w;
    }
    float* comb = smem + 8192;
    #pragma unroll
    for (int j = 0; j < 16; ++j) comb[(w*16 + j)*64 + lane] = acc[j];
    __syncthreads();
    if (tid < 256){
        int i = tid >> 6, b2 = tid & 63;
        float g4[4];
        #pragma unroll
        for (int q = 0; q < 4; ++q){
            float s = bl[q*1024 + r0 + i];
            #pragma unroll
            for (int ks = 0; ks < 8; ++ks) s += comb[(ks*16 + q*4 + i)*64 + b2];
            g4[q] = s;
        }
        int ri = (r0 + i)*64 + b2;
        float cn = sigmoidf(g4[1])*c_t[ri] + sigmoidf(g4[0])*tanhf(g4[2]);
        float hn = sigmoidf(g4[3])*tanhf(cn);
        c_t[ri] = cn;
        ht[ri] = hn;
        if (t >= T_READ)
            __builtin_nontemporal_store(hn, &hist[((size_t)(t-T_READ)*K5K + r0 + i)*64 + b2]);
    }
}

// ---------- K2: head-param partials pp[ks][col][b]. grid 262 x 256 ----------
__global__ __launch_bounds__(256) void k2_heads(
    const float* __restrict__ ht, const float* __restrict__ Wh, float* __restrict__ pp)
{
    const int lane = threadIdx.x & 63;
    const int wid  = blockIdx.x*4 + (threadIdx.x >> 6);   // 0..1047
    const int cg = wid % 131, ks = wid / 131;
    const int j0 = cg*4;
    const int k0 = ks*128;
    float ax=0.f, ay=0.f, az=0.f, aw=0.f;
    #pragma unroll 4
    for (int k = k0; k < k0+128; ++k){
        float a = ht[(size_t)k*64 + lane];
        float4 wv = *reinterpret_cast<const float4*>(Wh + (size_t)k*HD + j0);
        ax += a*wv.x; ay += a*wv.y; az += a*wv.z; aw += a*wv.w;
    }
    pp[((size_t)ks*HD + j0+0)*64 + lane] = ax;
    pp[((size_t)ks*HD + j0+1)*64 + lane] = ay;
    pp[((size_t)ks*HD + j0+2)*64 + lane] = az;
    pp[((size_t)ks*HD + j0+3)*64 + lane] = aw;
}

// ---------- K3: khat recompute + Mem row norms + content dots. grid 256 (b,nq) x 512 ----------
__global__ __launch_bounds__(512) void k3_dots(
    const float* __restrict__ pp, const float* __restrict__ bh, const float* __restrict__ Mem,
    float* __restrict__ mnorm, float* __restrict__ dots)
{
    __shared__ float kh[256];
    const int b = blockIdx.x >> 2, nq = blockIdx.x & 3;
    const int tid = threadIdx.x, lane = tid & 63, w = tid >> 6;
    if (tid < 256){
        int head = tid >> 7, m = tid & 127;
        int col = head ? (134 + m) : m;
        float v = bh[col];
        #pragma unroll
        for (int ks = 0; ks < 8; ++ks) v += pp[((size_t)ks*HD + col)*64 + b];
        kh[tid] = tanhf(v);
    }
    __syncthreads();
    float2 kr  = reinterpret_cast<const float2*>(kh)[lane];
    float2 kw2 = reinterpret_cast<const float2*>(kh + 128)[lane];
    #pragma unroll 2
    for (int i = 0; i < 16; ++i){
        int n = nq*128 + w*16 + i;
        const float* mrow = Mem + ((size_t)b*N + n)*M;
        float mx = __builtin_nontemporal_load(mrow + lane*2);
        float my = __builtin_nontemporal_load(mrow + lane*2 + 1);
        float s2 = mx*mx + my*my;
        float dr = mx*kr.x + my*kr.y;
        float dw = mx*kw2.x + my*kw2.y;
        #pragma unroll
        for (int off = 32; off; off >>= 1){
            s2 += __shfl_xor(s2, off);
            dr += __shfl_xor(dr, off);
            dw += __shfl_xor(dw, off);
        }
        if (lane == 0){
            mnorm[b*N + n] = sqrtf(s2);
            dots[(b*2+0)*N + n] = dr;
            dots[(b*2+1)*N + n] = dw;
        }
    }
}

__device__ __forceinline__ float blk_sum8(float v, volatile float* red8, int lane, int wv){
    #pragma unroll
    for (int off = 32; off; off >>= 1) v += __shfl_xor(v, off);
    if (lane == 0) red8[wv] = v;
    __syncthreads();
    float r = red8[0]+red8[1]+red8[2]+red8[3]+red8[4]+red8[5]+red8[6]+red8[7];
    __syncthreads();
    return r;
}
__device__ __forceinline__ float blk_max8(float v, volatile float* red8, int lane, int wv){
    #pragma unroll
    for (int off = 32; off; off >>= 1) v = fmaxf(v, __shfl_xor(v, off));
    if (lane == 0) red8[wv] = v;
    __syncthreads();
    float r = fmaxf(fmaxf(fmaxf(red8[0],red8[1]),fmaxf(red8[2],red8[3])),
                    fmaxf(fmaxf(red8[4],red8[5]),fmaxf(red8[6],red8[7])));
    __syncthreads();
    return r;
}

// ---------- K4: params recompute + redundant addressing + Mem update + reads. grid 256 (b,nq) x 512 ----------
__global__ __launch_bounds__(512) void k4_addr(
    const float* __restrict__ pp, const float* __restrict__ bh,
    const float* __restrict__ mnorm, const float* __restrict__ dots,
    float* __restrict__ wst, float* __restrict__ Mem, float* __restrict__ rp, int t)
{
    __shared__ float kh[256];
    __shared__ float sc[12];
    __shared__ float eal[256];
    __shared__ float wr_s[512], ww_s[512], wg[512];
    __shared__ float red8[8];
    __shared__ float racc_s[512];
    const int b = blockIdx.x >> 2, nq = blockIdx.x & 3;
    const int tid = threadIdx.x, lane = tid & 63, wv8 = tid >> 6;

    // phase A: finalize khat / scal / erase,add from pp
    if (tid < 256){
        int head = tid >> 7, m = tid & 127;
        int col = head ? (134 + m) : m;
        float v = bh[col];
        #pragma unroll
        for (int ks = 0; ks < 8; ++ks) v += pp[((size_t)ks*HD + col)*64 + b];
        kh[tid] = tanhf(v);
    } else if (tid < 268){
        int i = tid - 256;                    // 0..11
        int ii = (i < 6) ? i : i - 6;
        int col = (i < 6) ? (128 + ii) : (262 + ii);
        float v = bh[col];
        #pragma unroll
        for (int ks = 0; ks < 8; ++ks) v += pp[((size_t)ks*HD + col)*64 + b];
        sc[i] = (ii==0) ? softplusf(v) : (ii==1) ? sigmoidf(v) : (ii==5) ? 1.f+softplusf(v) : v;
    } else if (tid < 524){
        int j = tid - 268;                    // 0..255
        int col = 268 + j;
        float v = bh[col];
        #pragma unroll
        for (int ks = 0; ks < 8; ++ks) v += pp[((size_t)ks*HD + col)*64 + b];
        eal[j] = (j < 128) ? sigmoidf(v) : tanhf(v);
    }
    __syncthreads();

    // phase B: addressing for both heads (redundant across 4 sibling blocks)
    const int n = tid;
    #pragma unroll 1
    for (int head = 0; head < 2; ++head){
        float kv = (n < 128) ? kh[head*128 + n] : 0.f;
        float knm = sqrtf(blk_sum8(kv*kv, red8, lane, wv8));
        float beta = sc[head*6+0], gg = sc[head*6+1], gamma = sc[head*6+5];
        float s0r = sc[head*6+2], s1r = sc[head*6+3], s2r = sc[head*6+4];
        float smx = fmaxf(s0r, fmaxf(s1r, s2r));
        float e0 = expf(s0r-smx), e1 = expf(s1r-smx), e2 = expf(s2r-smx);
        float esum = e0+e1+e2;
        float s0 = e0/esum, s1 = e1/esum, s2 = e2/esum;

        float sim = dots[(b*2+head)*N + n] / (mnorm[b*N + n]*knm + EPS);
        float aa = beta * sim;
        float amax = blk_max8(aa, red8, lane, wv8);
        float ev = expf(aa - amax);
        float wc = ev / blk_sum8(ev, red8, lane, wv8);

        const float* wpr = wst + ((size_t)((t&1)*2 + head))*(B*N);
        float*       wnx = wst + ((size_t)(((t+1)&1)*2 + head))*(B*N);
        float wprev = wpr[b*N + n];
        float wgv = gg*wc + (1.f - gg)*wprev;
        wg[n] = wgv; __syncthreads();
        float wsv = s0*wg[(n+1)&511] + s1*wgv + s2*wg[(n-1)&511];
        float wp2 = powf(wsv + EPS, gamma);
        float wsum = blk_sum8(wp2, red8, lane, wv8);
        float wv = wp2 / wsum;
        (head ? ww_s : wr_s)[n] = wv;
        if (nq == 0) wnx[b*N + n] = wv;
        __syncthreads();
    }

    // phase C: read (old Mem) + erase/add on own (b,nq) slice — nontemporal
    {
        const int m = tid & 127, ns = tid >> 7;
        const float e  = eal[m];
        const float ad = eal[128 + m];
        float racc = 0.f;
        #pragma unroll 4
        for (int i2 = 0; i2 < 32; ++i2){
            int nn = nq*128 + i2*4 + ns;
            size_t idx = ((size_t)b*N + nn)*M + m;
            float v = __builtin_nontemporal_load(&Mem[idx]);
            float wr = wr_s[nn], ww = ww_s[nn];
            racc += wr*v;
            __builtin_nontemporal_store(v*(1.f - ww*e) + ww*ad, &Mem[idx]);
        }
        __syncthreads();
        racc_s[tid] = racc;
        __syncthreads();
        if (tid < 128){
            float s = racc_s[tid] + racc_s[128+tid] + racc_s[256+tid] + racc_s[384+tid];
            rp[(size_t)nq*8192 + tid*64 + b] = s;
        }
    }
}

// ---------- k_fin: last step's reads -> hist. grid 32 x 256 ----------
__global__ __launch_bounds__(256) void k_fin(const float* __restrict__ rp, float* __restrict__ hist){
    int e = blockIdx.x*256 + threadIdx.x;
    float s = rp[e] + rp[8192+e] + rp[16384+e] + rp[24576+e];
    __builtin_nontemporal_store(s, &hist[((size_t)31*K5K + 1024 + (e>>6))*64 + (e&63)]);
}

// ---------- K5: out = sigmoid([h, reads]·Wo + bo), all 32 write steps. grid 256 x 512 ----------
__global__ __launch_bounds__(512) void k5_out(
    const float* __restrict__ hist, const float* __restrict__ Wo, const float* __restrict__ bo,
    float* __restrict__ out)
{
    __shared__ float smem[16384];
    const int tid = threadIdx.x, lane = tid & 63, w = tid >> 6;
    const int l = blockIdx.x >> 3, jg = blockIdx.x & 7;
    const int j0 = jg*32;
    float acc[32];
    #pragma unroll
    for (int i = 0; i < 32; ++i) acc[i] = 0.f;
    const int k0 = w*144;
    #pragma unroll 2
    for (int kk = 0; kk < 144; ++kk){
        int k = k0 + kk;
        float a = __builtin_nontemporal_load(&hist[((size_t)l*K5K + k)*64 + lane]);
        const float* wrow = Wo + (size_t)k*D + j0;
        #pragma unroll
        for (int qq = 0; qq < 8; ++qq){
            float4 wv = *reinterpret_cast<const float4*>(wrow + qq*4);
            acc[qq*4+0] += a*wv.x; acc[qq*4+1] += a*wv.y;
            acc[qq*4+2] += a*wv.z; acc[qq*4+3] += a*wv.w;
        }
    }
    __syncthreads();
    #pragma unroll
    for (int c = 0; c < 32; ++c) smem[(w*32 + c)*64 + lane] = acc[c];
    __syncthreads();
    {
        const int b2 = tid >> 3, jq = tid & 7;
        float4 ov;
        float* po = (float*)&ov;
        #pragma unroll
        for (int i = 0; i < 4; ++i){
            int c = jq*4 + i;
            float s = bo[j0 + c];
            #pragma unroll
            for (int ks = 0; ks < 8; ++ks) s += smem[(ks*32 + c)*64 + b2];
            po[i] = sigmoidf(s);
        }
        *reinterpret_cast<float4*>(out + ((size_t)b2*L_WRITE + l)*D + j0 + jq*4) = ov;
    }
}

extern "C" void kernel_launch(void* const* d_in, const int* in_sizes, int n_in,
                              void* d_out, int out_size, void* d_ws, size_t ws_size,
                              hipStream_t stream)
{
    const float* x   = (const float*)d_in[0];
    const float* Wl  = (const float*)d_in[1];
    const float* Ul  = (const float*)d_in[2];
    const float* bl  = (const float*)d_in[3];
    const float* Wh  = (const float*)d_in[4];
    const float* bh  = (const float*)d_in[5];
    const float* Wo  = (const float*)d_in[6];
    const float* bo  = (const float*)d_in[7];
    float* out = (float*)d_out;

    float* ws = (float*)d_ws;
    float* xT    = ws; ws += (size_t)T_READ*D*64;       // 8.4 MB
    float* Wre   = ws; ws += (size_t)1408*4096;         // 23 MB
    float* ht    = ws; ws += (size_t)R*64;
    float* c_t   = ws; ws += (size_t)R*64;
    float* pp    = ws; ws += (size_t)8*HD*64;           // 1.07 MB
    float* mnorm = ws; ws += (size_t)B*N;
    float* dots  = ws; ws += (size_t)B*2*N;
    float* wst   = ws; ws += (size_t)4*B*N;             // parity x head
    float* Mem   = ws; ws += (size_t)B*N*M;             // 16.8 MB
    float* rp    = ws; ws += (size_t)4*128*64;
    float* hist  = ws; ws += (size_t)L_WRITE*K5K*64;    // 9.4 MB

    hipLaunchKernelGGL(kx_transpose, dim3(T_READ*4), dim3(256), 0, stream, x, xT);
    hipLaunchKernelGGL(kpack_w,      dim3(1408),     dim3(256), 0, stream, Wl, Ul, Wre);
    hipLaunchKernelGGL(k_init,       dim3(2048),     dim3(256), 0, stream, ht, c_t, rp, wst, Mem);

    for (int t = 0; t < TT; ++t){
        hipLaunchKernelGGL(k1_z,     dim3(256), dim3(512), 0, stream, xT, Wre, bl, ht, c_t, rp, hist, t);
        hipLaunchKernelGGL(k2_heads, dim3(262), dim3(256), 0, stream, ht, Wh, pp);
        hipLaunchKernelGGL(k3_dots,  dim3(256), dim3(512), 0, stream, pp, bh, Mem, mnorm, dots);
        hipLaunchKernelGGL(k4_addr,  dim3(256), dim3(512), 0, stream, pp, bh, mnorm, dots, wst, Mem, rp, t);
    }
    hipLaunchKernelGGL(k_fin,  dim3(32),  dim3(256), 0, stream, rp, hist);
    hipLaunchKernelGGL(k5_out, dim3(256), dim3(512), 0, stream, hist, Wo, bo, out);
}

// Round 14
// 13368.958 us; speedup vs baseline: 1.3353x; 1.3353x over previous
//
#include <hip/hip_runtime.h>
#include <math.h>

#define B 64
#define T_READ 128
#define L_WRITE 32
#define TT 160
#define D 256
#define R 1024
#define N 512
#define M 128
#define HD 524
#define K5K 1152
#define EPS 1e-8f

__device__ __forceinline__ float sigmoidf(float x){ return 1.0f/(1.0f+expf(-x)); }
__device__ __forceinline__ float softplusf(float x){ return (x > 20.f) ? x : log1pf(expf(x)); }

// ---------- one-time: transpose x -> xT[t][k][b] ----------
__global__ __launch_bounds__(256) void kx_transpose(const float* __restrict__ x, float* __restrict__ xT){
    __shared__ float tile[64][65];
    const int t = blockIdx.x >> 2, k0 = (blockIdx.x & 3)*64;
    #pragma unroll
    for (int rep = 0; rep < 16; ++rep){
        int idx = rep*256 + threadIdx.x;
        int bl = idx >> 6, kl = idx & 63;
        tile[bl][kl] = x[((size_t)bl*T_READ + t)*D + k0 + kl];
    }
    __syncthreads();
    #pragma unroll
    for (int rep = 0; rep < 16; ++rep){
        int idx = rep*256 + threadIdx.x;
        int kl = idx >> 6, bl = idx & 63;
        xT[((size_t)t*D + k0 + kl)*64 + bl] = tile[bl][kl];
    }
}

// ---------- one-time: pack Wl/Ul into per-block-contiguous Wre[bk][k][16] ----------
__global__ __launch_bounds__(256) void kpack_w(const float* __restrict__ Wl, const float* __restrict__ Ul,
                                               float* __restrict__ Wre){
    const int k = blockIdx.x;                 // 0..1407
    const float* src = (k < 384) ? (Wl + (size_t)k*4096) : (Ul + (size_t)(k-384)*4096);
    #pragma unroll
    for (int it = 0; it < 16; ++it){
        int j = it*256 + threadIdx.x;         // 0..4095
        int bk = j >> 4, r = j & 15, q = r >> 2, i = r & 3;
        Wre[((size_t)bk*1408 + k)*16 + r] = src[q*1024 + bk*4 + i];
    }
}

// ---------- one-time: init state ----------
__global__ void k_init(float* ht, float* c_t, float* rp, float* wst, float* Mem){
    int idx = blockIdx.x*blockDim.x + threadIdx.x;
    int stride = gridDim.x*blockDim.x;
    for (int i = idx; i < B*N*M; i += stride) Mem[i] = 1e-6f;
    for (int i = idx; i < R*64; i += stride){ ht[i]=0.f; c_t[i]=0.f; }
    for (int i = idx; i < 4*128*64; i += stride) rp[i] = 0.f;
    for (int i = idx; i < 2*B*N; i += stride) wst[i] = 1.f/512.f;   // parity-0, both heads
}

// ---------- K1: combine reads; z = W·[x,reads] + U·h + b; LSTM gates. grid 256 x 1024 ----------
__global__ __launch_bounds__(1024) void k1_z(
    const float* __restrict__ xT, const float* __restrict__ Wre, const float* __restrict__ bl,
    float* __restrict__ ht, float* __restrict__ c_t, const float* __restrict__ rp,
    float* __restrict__ hist, int t)
{
    __shared__ float smem[8192 + 16384];   // [0,8192) reads staging, comb 16x16x64
    const int bk = blockIdx.x;
    const int tid = threadIdx.x, lane = tid & 63, w = tid >> 6;   // w: 0..15

    for (int e = tid; e < 8192; e += 1024){
        float s = rp[e] + rp[8192+e] + rp[16384+e] + rp[24576+e];
        smem[e] = s;
        if (t > T_READ && (e >> 10) == bk)   // blocks 0..7 write their slice once
            hist[((size_t)(t-1-T_READ)*K5K + 1024 + (e>>6))*64 + (e&63)] = s;
    }
    __syncthreads();

    const int r0 = bk*4;
    const int rd = (t < T_READ);
    const int kn = rd ? 88 : 72;
    const int k0 = rd ? w*88 : 256 + w*72;
    const float* wbase = Wre + ((size_t)bk*1408 + k0)*16;
    float acc[16];
    #pragma unroll
    for (int i = 0; i < 16; ++i) acc[i] = 0.f;
    #pragma unroll 4
    for (int kk = 0; kk < kn; ++kk){
        int k = k0 + kk;
        float a;
        if (k < 256)      a = xT[((size_t)t*256 + k)*64 + lane];
        else if (k < 384) a = smem[(k-256)*64 + lane];
        else              a = ht[(size_t)(k-384)*64 + lane];
        const float4* wv4 = reinterpret_cast<const float4*>(wbase + (size_t)kk*16);
        float4 w0 = wv4[0], w1 = wv4[1], w2 = wv4[2], w3 = wv4[3];
        acc[0]+=a*w0.x;  acc[1]+=a*w0.y;  acc[2]+=a*w0.z;  acc[3]+=a*w0.w;
        acc[4]+=a*w1.x;  acc[5]+=a*w1.y;  acc[6]+=a*w1.z;  acc[7]+=a*w1.w;
        acc[8]+=a*w2.x;  acc[9]+=a*w2.y;  acc[10]+=a*w2.z; acc[11]+=a*w2.w;
        acc[12]+=a*w3.x; acc[13]+=a*w3.y; acc[14]+=a*w3.z; acc[15]+=a*w3.w;
    }
    float* comb = smem + 8192;
    #pragma unroll
    for (int j = 0; j < 16; ++j) comb[(w*16 + j)*64 + lane] = acc[j];
    __syncthreads();
    if (tid < 256){
        int i = tid >> 6, b2 = tid & 63;
        float g4[4];
        #pragma unroll
        for (int q = 0; q < 4; ++q){
            float s = bl[q*1024 + r0 + i];
            #pragma unroll
            for (int ks = 0; ks < 16; ++ks) s += comb[(ks*16 + q*4 + i)*64 + b2];
            g4[q] = s;
        }
        int ri = (r0 + i)*64 + b2;
        float cn = sigmoidf(g4[1])*c_t[ri] + sigmoidf(g4[0])*tanhf(g4[2]);
        float hn = sigmoidf(g4[3])*tanhf(cn);
        c_t[ri] = cn;
        ht[ri] = hn;
        if (t >= T_READ) hist[((size_t)(t-T_READ)*K5K + r0 + i)*64 + b2] = hn;
    }
}

// ---------- K2: head-param partials pp[b][ks][col]. grid 524 x 256, 16-way ksplit ----------
__global__ __launch_bounds__(256) void k2_heads(
    const float* __restrict__ ht, const float* __restrict__ Wh, float* __restrict__ pp)
{
    const int lane = threadIdx.x & 63;
    const int wid  = blockIdx.x*4 + (threadIdx.x >> 6);   // 0..2095
    const int cg = wid % 131, ks = wid / 131;             // ks: 0..15
    const int j0 = cg*4;
    const int k0 = ks*64;
    float ax=0.f, ay=0.f, az=0.f, aw=0.f;
    #pragma unroll 4
    for (int k = k0; k < k0+64; ++k){
        float a = ht[(size_t)k*64 + lane];
        float4 wv = *reinterpret_cast<const float4*>(Wh + (size_t)k*HD + j0);
        ax += a*wv.x; ay += a*wv.y; az += a*wv.z; aw += a*wv.w;
    }
    float* dst = pp + ((size_t)lane*16 + ks)*HD + j0;
    dst[0]=ax; dst[1]=ay; dst[2]=az; dst[3]=aw;
}

// ---------- K3: khat recompute + Mem row norms + content dots. grid 512 (b, nq0..7) x 512 ----------
__global__ __launch_bounds__(512) void k3_dots(
    const float* __restrict__ pp, const float* __restrict__ bh, const float* __restrict__ Mem,
    float* __restrict__ mnorm, float* __restrict__ dots)
{
    __shared__ float kh[256];
    const int b = blockIdx.x >> 3, nq = blockIdx.x & 7;
    const int tid = threadIdx.x, lane = tid & 63, w = tid >> 6;   // w: 0..7
    const float* pp_b = pp + (size_t)b*16*HD;
    if (tid < 256){
        int head = tid >> 7, m = tid & 127;
        int col = head ? (134 + m) : m;
        float v = bh[col];
        #pragma unroll
        for (int ks = 0; ks < 16; ++ks) v += pp_b[ks*HD + col];
        kh[tid] = tanhf(v);
    }
    __syncthreads();
    float2 kr  = reinterpret_cast<const float2*>(kh)[lane];
    float2 kw2 = reinterpret_cast<const float2*>(kh + 128)[lane];
    #pragma unroll 2
    for (int i = 0; i < 8; ++i){
        int n = nq*64 + w*8 + i;
        const float* mrow = Mem + ((size_t)b*N + n)*M;
        float2 mv = *reinterpret_cast<const float2*>(mrow + lane*2);
        float s2 = mv.x*mv.x + mv.y*mv.y;
        float dr = mv.x*kr.x + mv.y*kr.y;
        float dw = mv.x*kw2.x + mv.y*kw2.y;
        #pragma unroll
        for (int off = 32; off; off >>= 1){
            s2 += __shfl_xor(s2, off);
            dr += __shfl_xor(dr, off);
            dw += __shfl_xor(dw, off);
        }
        if (lane == 0){
            mnorm[b*N + n] = sqrtf(s2);
            dots[(b*2+0)*N + n] = dr;
            dots[(b*2+1)*N + n] = dw;
        }
    }
}

// group-local (512-thread) reductions; both halves call in lockstep
__device__ __forceinline__ float blk_sum8g(float v, volatile float* red8, int lane, int wgi){
    #pragma unroll
    for (int off = 32; off; off >>= 1) v += __shfl_xor(v, off);
    if (lane == 0) red8[wgi] = v;
    __syncthreads();
    float r = red8[0]+red8[1]+red8[2]+red8[3]+red8[4]+red8[5]+red8[6]+red8[7];
    __syncthreads();
    return r;
}
__device__ __forceinline__ float blk_max8g(float v, volatile float* red8, int lane, int wgi){
    #pragma unroll
    for (int off = 32; off; off >>= 1) v = fmaxf(v, __shfl_xor(v, off));
    if (lane == 0) red8[wgi] = v;
    __syncthreads();
    float r = fmaxf(fmaxf(fmaxf(red8[0],red8[1]),fmaxf(red8[2],red8[3])),
                    fmaxf(fmaxf(red8[4],red8[5]),fmaxf(red8[6],red8[7])));
    __syncthreads();
    return r;
}

// ---------- K4: params finalize + redundant addressing (heads parallel) + Mem update + reads ----------
// grid 256 (b,nq) x 1024
__global__ __launch_bounds__(1024) void k4_addr(
    const float* __restrict__ pp, const float* __restrict__ bh,
    const float* __restrict__ mnorm, const float* __restrict__ dots,
    float* __restrict__ wst, float* __restrict__ Mem, float* __restrict__ rp, int t)
{
    __shared__ float kh[256];
    __shared__ float sc[12];
    __shared__ float eal[256];
    __shared__ float wfin[1024];
    __shared__ float wgbuf[1024];
    __shared__ float red8[2][8];
    __shared__ float racc_s[1024];
    const int b = blockIdx.x >> 2, nq = blockIdx.x & 3;
    const int tid = threadIdx.x, lane = tid & 63;
    const float* pp_b = pp + (size_t)b*16*HD;

    // phase A: finalize khat / scal / erase,add from contiguous pp slice
    if (tid < 256){
        int head = tid >> 7, m = tid & 127;
        int col = head ? (134 + m) : m;
        float v = bh[col];
        #pragma unroll
        for (int ks = 0; ks < 16; ++ks) v += pp_b[ks*HD + col];
        kh[tid] = tanhf(v);
    } else if (tid < 268){
        int i = tid - 256;                    // 0..11
        int ii = (i < 6) ? i : i - 6;
        int col = (i < 6) ? (128 + ii) : (262 + ii);
        float v = bh[col];
        #pragma unroll
        for (int ks = 0; ks < 16; ++ks) v += pp_b[ks*HD + col];
        sc[i] = (ii==0) ? softplusf(v) : (ii==1) ? sigmoidf(v) : (ii==5) ? 1.f+softplusf(v) : v;
    } else if (tid < 524){
        int j = tid - 268;                    // 0..255
        int col = 268 + j;
        float v = bh[col];
        #pragma unroll
        for (int ks = 0; ks < 16; ++ks) v += pp_b[ks*HD + col];
        eal[j] = (j < 128) ? sigmoidf(v) : tanhf(v);
    }
    __syncthreads();

    // phase B: addressing, both heads in parallel 512-thread halves (redundant across siblings)
    {
        const int g = tid >> 9;          // head
        const int n = tid & 511;
        const int wgi = (tid >> 6) & 7;
        float* wgl = wgbuf + g*512;
        volatile float* r8 = red8[g];

        float kv = (n < 128) ? kh[g*128 + n] : 0.f;
        float knm = sqrtf(blk_sum8g(kv*kv, r8, lane, wgi));
        float beta = sc[g*6+0], gg = sc[g*6+1], gamma = sc[g*6+5];
        float s0r = sc[g*6+2], s1r = sc[g*6+3], s2r = sc[g*6+4];
        float smx = fmaxf(s0r, fmaxf(s1r, s2r));
        float e0 = expf(s0r-smx), e1 = expf(s1r-smx), e2 = expf(s2r-smx);
        float esum = e0+e1+e2;
        float s0 = e0/esum, s1 = e1/esum, s2 = e2/esum;

        float sim = dots[(b*2+g)*N + n] / (mnorm[b*N + n]*knm + EPS);
        float aa = beta * sim;
        float amax = blk_max8g(aa, r8, lane, wgi);
        float ev = expf(aa - amax);
        float wc = ev / blk_sum8g(ev, r8, lane, wgi);

        const float* wpr = wst + ((size_t)((t&1)*2 + g))*(B*N);
        float*       wnx = wst + ((size_t)(((t+1)&1)*2 + g))*(B*N);
        float wprev = wpr[b*N + n];
        float wgv = gg*wc + (1.f - gg)*wprev;
        wgl[n] = wgv; __syncthreads();
        float wsv = s0*wgl[(n+1)&511] + s1*wgv + s2*wgl[(n-1)&511];
        float wp2 = powf(wsv + EPS, gamma);
        float wsum = blk_sum8g(wp2, r8, lane, wgi);
        float wv = wp2 / wsum;
        wfin[g*512 + n] = wv;
        if (nq == 0) wnx[b*N + n] = wv;
        __syncthreads();
    }

    // phase C: read (old Mem) + erase/add on own (b,nq) slice of 128 rows
    {
        const int m = tid & 127, ns = tid >> 7;   // 8 row-groups
        const float e  = eal[m];
        const float ad = eal[128 + m];
        float racc = 0.f;
        #pragma unroll 4
        for (int i2 = 0; i2 < 16; ++i2){
            int nn = nq*128 + i2*8 + ns;
            size_t idx = ((size_t)b*N + nn)*M + m;
            float v = Mem[idx];
            float wr = wfin[nn], ww = wfin[512 + nn];
            racc += wr*v;
            Mem[idx] = v*(1.f - ww*e) + ww*ad;
        }
        racc_s[tid] = racc;
        __syncthreads();
        if (tid < 128){
            float s = 0.f;
            #pragma unroll
            for (int g2 = 0; g2 < 8; ++g2) s += racc_s[g2*128 + tid];
            rp[(size_t)nq*8192 + tid*64 + b] = s;
        }
    }
}

// ---------- k_fin: last step's reads -> hist. grid 32 x 256 ----------
__global__ __launch_bounds__(256) void k_fin(const float* __restrict__ rp, float* __restrict__ hist){
    int e = blockIdx.x*256 + threadIdx.x;
    float s = rp[e] + rp[8192+e] + rp[16384+e] + rp[24576+e];
    hist[((size_t)31*K5K + 1024 + (e>>6))*64 + (e&63)] = s;
}

// ---------- K5: out = sigmoid([h, reads]·Wo + bo), all 32 write steps. grid 256 x 512 ----------
__global__ __launch_bounds__(512) void k5_out(
    const float* __restrict__ hist, const float* __restrict__ Wo, const float* __restrict__ bo,
    float* __restrict__ out)
{
    __shared__ float smem[16384];
    const int tid = threadIdx.x, lane = tid & 63, w = tid >> 6;
    const int l = blockIdx.x >> 3, jg = blockIdx.x & 7;
    const int j0 = jg*32;
    float acc[32];
    #pragma unroll
    for (int i = 0; i < 32; ++i) acc[i] = 0.f;
    const int k0 = w*144;
    #pragma unroll 2
    for (int kk = 0; kk < 144; ++kk){
        int k = k0 + kk;
        float a = hist[((size_t)l*K5K + k)*64 + lane];
        const float* wrow = Wo + (size_t)k*D + j0;
        #pragma unroll
        for (int qq = 0; qq < 8; ++qq){
            float4 wv = *reinterpret_cast<const float4*>(wrow + qq*4);
            acc[qq*4+0] += a*wv.x; acc[qq*4+1] += a*wv.y;
            acc[qq*4+2] += a*wv.z; acc[qq*4+3] += a*wv.w;
        }
    }
    __syncthreads();
    #pragma unroll
    for (int c = 0; c < 32; ++c) smem[(w*32 + c)*64 + lane] = acc[c];
    __syncthreads();
    {
        const int b2 = tid >> 3, jq = tid & 7;
        float4 ov;
        float* po = (float*)&ov;
        #pragma unroll
        for (int i = 0; i < 4; ++i){
            int c = jq*4 + i;
            float s = bo[j0 + c];
            #pragma unroll
            for (int ks = 0; ks < 8; ++ks) s += smem[(ks*32 + c)*64 + b2];
            po[i] = sigmoidf(s);
        }
        *reinterpret_cast<float4*>(out + ((size_t)b2*L_WRITE + l)*D + j0 + jq*4) = ov;
    }
}

extern "C" void kernel_launch(void* const* d_in, const int* in_sizes, int n_in,
                              void* d_out, int out_size, void* d_ws, size_t ws_size,
                              hipStream_t stream)
{
    const float* x   = (const float*)d_in[0];
    const float* Wl  = (const float*)d_in[1];
    const float* Ul  = (const float*)d_in[2];
    const float* bl  = (const float*)d_in[3];
    const float* Wh  = (const float*)d_in[4];
    const float* bh  = (const float*)d_in[5];
    const float* Wo  = (const float*)d_in[6];
    const float* bo  = (const float*)d_in[7];
    float* out = (float*)d_out;

    float* ws = (float*)d_ws;
    float* xT    = ws; ws += (size_t)T_READ*D*64;       // 8.4 MB
    float* Wre   = ws; ws += (size_t)1408*4096;         // 23 MB
    float* ht    = ws; ws += (size_t)R*64;
    float* c_t   = ws; ws += (size_t)R*64;
    float* pp    = ws; ws += (size_t)B*16*HD;           // 2.1 MB  [b][ks][col]
    float* mnorm = ws; ws += (size_t)B*N;
    float* dots  = ws; ws += (size_t)B*2*N;
    float* wst   = ws; ws += (size_t)4*B*N;             // parity x head
    float* Mem   = ws; ws += (size_t)B*N*M;             // 16.8 MB
    float* rp    = ws; ws += (size_t)4*128*64;
    float* hist  = ws; ws += (size_t)L_WRITE*K5K*64;    // 9.4 MB

    hipLaunchKernelGGL(kx_transpose, dim3(T_READ*4), dim3(256), 0, stream, x, xT);
    hipLaunchKernelGGL(kpack_w,      dim3(1408),     dim3(256), 0, stream, Wl, Ul, Wre);
    hipLaunchKernelGGL(k_init,       dim3(2048),     dim3(256), 0, stream, ht, c_t, rp, wst, Mem);

    for (int t = 0; t < TT; ++t){
        hipLaunchKernelGGL(k1_z,     dim3(256), dim3(1024), 0, stream, xT, Wre, bl, ht, c_t, rp, hist, t);
        hipLaunchKernelGGL(k2_heads, dim3(524), dim3(256),  0, stream, ht, Wh, pp);
        hipLaunchKernelGGL(k3_dots,  dim3(512), dim3(512),  0, stream, pp, bh, Mem, mnorm, dots);
        hipLaunchKernelGGL(k4_addr,  dim3(256), dim3(1024), 0, stream, pp, bh, mnorm, dots, wst, Mem, rp, t);
    }
    hipLaunchKernelGGL(k_fin,  dim3(32),  dim3(256), 0, stream, rp, hist);
    hipLaunchKernelGGL(k5_out, dim3(256), dim3(512), 0, stream, hist, Wo, bo, out);
}

// Round 15
// 11471.561 us; speedup vs baseline: 1.5561x; 1.1654x over previous
//
#include <hip/hip_runtime.h>
#include <hip/hip_fp16.h>
#include <math.h>

#define B 64
#define T_READ 128
#define L_WRITE 32
#define TT 160
#define D 256
#define R 1024
#define N 512
#define M 128
#define HD 524
#define K5K 1152
#define EPS 1e-8f
#define BNM ((size_t)B*N*M)

__device__ __forceinline__ float sigmoidf(float x){ return 1.0f/(1.0f+expf(-x)); }
__device__ __forceinline__ float softplusf(float x){ return (x > 20.f) ? x : log1pf(expf(x)); }

// ---------- one-time: transpose x -> xT[t][k][b] ----------
__global__ __launch_bounds__(256) void kx_transpose(const float* __restrict__ x, float* __restrict__ xT){
    __shared__ float tile[64][65];
    const int t = blockIdx.x >> 2, k0 = (blockIdx.x & 3)*64;
    #pragma unroll
    for (int rep = 0; rep < 16; ++rep){
        int idx = rep*256 + threadIdx.x;
        int bl = idx >> 6, kl = idx & 63;
        tile[bl][kl] = x[((size_t)bl*T_READ + t)*D + k0 + kl];
    }
    __syncthreads();
    #pragma unroll
    for (int rep = 0; rep < 16; ++rep){
        int idx = rep*256 + threadIdx.x;
        int kl = idx >> 6, bl = idx & 63;
        xT[((size_t)t*D + k0 + kl)*64 + bl] = tile[bl][kl];
    }
}

// ---------- one-time: pack Wl/Ul into per-block-contiguous fp16 Wreh[bk][k][16] ----------
__global__ __launch_bounds__(256) void kpack_w(const float* __restrict__ Wl, const float* __restrict__ Ul,
                                               __half* __restrict__ Wreh){
    const int k = blockIdx.x;                 // 0..1407
    const float* src = (k < 384) ? (Wl + (size_t)k*4096) : (Ul + (size_t)(k-384)*4096);
    #pragma unroll
    for (int it = 0; it < 16; ++it){
        int j = it*256 + threadIdx.x;         // 0..4095
        int bk = j >> 4, r = j & 15, q = r >> 2, i = r & 3;
        Wreh[((size_t)bk*1408 + k)*16 + r] = __float2half_rn(src[q*1024 + bk*4 + i]);
    }
}

// ---------- one-time: Wh -> fp16 copy ----------
__global__ __launch_bounds__(256) void kpack_wh(const float* __restrict__ Wh, __half* __restrict__ Whh){
    const int k = blockIdx.x;                 // 0..1023
    for (int j = threadIdx.x; j < HD; j += 256)
        Whh[(size_t)k*HD + j] = __float2half_rn(Wh[(size_t)k*HD + j]);
}

// ---------- one-time: init state ----------
__global__ void k_init(float* ht, float* c_t, float* rp, float* wst, __half* Mem){
    size_t idx = (size_t)blockIdx.x*blockDim.x + threadIdx.x;
    size_t stride = (size_t)gridDim.x*blockDim.x;
    const __half mi = __float2half(1e-6f);
    for (size_t i = idx; i < BNM; i += stride) Mem[i] = mi;
    for (size_t i = idx; i < R*64; i += stride){ ht[i]=0.f; c_t[i]=0.f; }
    for (size_t i = idx; i < 4*128*64; i += stride) rp[i] = 0.f;
    for (size_t i = idx; i < 2*B*N; i += stride) wst[i] = 1.f/512.f;
}

// ---------- K1: combine reads; z = W·[x,reads] + U·h + b; LSTM gates. grid 256 x 1024 ----------
__global__ __launch_bounds__(1024) void k1_z(
    const float* __restrict__ xT, const __half* __restrict__ Wreh, const float* __restrict__ bl,
    float* __restrict__ ht, float* __restrict__ c_t, const float* __restrict__ rp,
    float* __restrict__ hist, int t)
{
    __shared__ float smem[8192 + 16384];
    const int bk = blockIdx.x;
    const int tid = threadIdx.x, lane = tid & 63, w = tid >> 6;   // w: 0..15

    for (int e = tid; e < 8192; e += 1024){
        float s = rp[e] + rp[8192+e] + rp[16384+e] + rp[24576+e];
        smem[e] = s;
        if (t > T_READ && (e >> 10) == bk)
            hist[((size_t)(t-1-T_READ)*K5K + 1024 + (e>>6))*64 + (e&63)] = s;
    }
    __syncthreads();

    const int r0 = bk*4;
    const int rd = (t < T_READ);
    const int kn = rd ? 88 : 72;
    const int k0 = rd ? w*88 : 256 + w*72;
    const __half* wbase = Wreh + ((size_t)bk*1408 + k0)*16;
    float acc[16];
    #pragma unroll
    for (int i = 0; i < 16; ++i) acc[i] = 0.f;
    #pragma unroll 4
    for (int kk = 0; kk < kn; ++kk){
        int k = k0 + kk;
        float a;
        if (k < 256)      a = xT[((size_t)t*256 + k)*64 + lane];
        else if (k < 384) a = smem[(k-256)*64 + lane];
        else              a = ht[(size_t)(k-384)*64 + lane];
        float4 raw0 = *reinterpret_cast<const float4*>(wbase + (size_t)kk*16);
        float4 raw1 = *reinterpret_cast<const float4*>(wbase + (size_t)kk*16 + 8);
        const __half2* h0 = reinterpret_cast<const __half2*>(&raw0);
        const __half2* h1 = reinterpret_cast<const __half2*>(&raw1);
        float2 f;
        f = __half22float2(h0[0]); acc[0] += a*f.x; acc[1] += a*f.y;
        f = __half22float2(h0[1]); acc[2] += a*f.x; acc[3] += a*f.y;
        f = __half22float2(h0[2]); acc[4] += a*f.x; acc[5] += a*f.y;
        f = __half22float2(h0[3]); acc[6] += a*f.x; acc[7] += a*f.y;
        f = __half22float2(h1[0]); acc[8] += a*f.x; acc[9] += a*f.y;
        f = __half22float2(h1[1]); acc[10]+= a*f.x; acc[11]+= a*f.y;
        f = __half22float2(h1[2]); acc[12]+= a*f.x; acc[13]+= a*f.y;
        f = __half22float2(h1[3]); acc[14]+= a*f.x; acc[15]+= a*f.y;
    }
    float* comb = smem + 8192;
    #pragma unroll
    for (int j = 0; j < 16; ++j) comb[(w*16 + j)*64 + lane] = acc[j];
    __syncthreads();
    if (tid < 256){
        int i = tid >> 6, b2 = tid & 63;
        float g4[4];
        #pragma unroll
        for (int q = 0; q < 4; ++q){
            float s = bl[q*1024 + r0 + i];
            #pragma unroll
            for (int ks = 0; ks < 16; ++ks) s += comb[(ks*16 + q*4 + i)*64 + b2];
            g4[q] = s;
        }
        int ri = (r0 + i)*64 + b2;
        float cn = sigmoidf(g4[1])*c_t[ri] + sigmoidf(g4[0])*tanhf(g4[2]);
        float hn = sigmoidf(g4[3])*tanhf(cn);
        c_t[ri] = cn;
        ht[ri] = hn;
        if (t >= T_READ) hist[((size_t)(t-T_READ)*K5K + r0 + i)*64 + b2] = hn;
    }
}

// ---------- K2: head-param partials pp[b][ks][col]. grid 524 x 256, 16-way ksplit ----------
__global__ __launch_bounds__(256) void k2_heads(
    const float* __restrict__ ht, const __half* __restrict__ Whh, float* __restrict__ pp)
{
    const int lane = threadIdx.x & 63;
    const int wid  = blockIdx.x*4 + (threadIdx.x >> 6);   // 0..2095
    const int cg = wid % 131, ks = wid / 131;             // ks: 0..15
    const int j0 = cg*4;
    const int k0 = ks*64;
    float ax=0.f, ay=0.f, az=0.f, aw=0.f;
    #pragma unroll 4
    for (int k = k0; k < k0+64; ++k){
        float a = ht[(size_t)k*64 + lane];
        float2 raw = *reinterpret_cast<const float2*>(Whh + (size_t)k*HD + j0);
        const __half2* hp = reinterpret_cast<const __half2*>(&raw);
        float2 w01 = __half22float2(hp[0]), w23 = __half22float2(hp[1]);
        ax += a*w01.x; ay += a*w01.y; az += a*w23.x; aw += a*w23.y;
    }
    float* dst = pp + ((size_t)lane*16 + ks)*HD + j0;
    dst[0]=ax; dst[1]=ay; dst[2]=az; dst[3]=aw;
}

// ---------- K3: khat recompute + Mem row norms + content dots. grid 512 (b, nq0..7) x 512 ----------
__global__ __launch_bounds__(512) void k3_dots(
    const float* __restrict__ pp, const float* __restrict__ bh, const __half* __restrict__ Mem,
    float* __restrict__ mnorm, float* __restrict__ dots)
{
    __shared__ float kh[256];
    const int b = blockIdx.x >> 3, nq = blockIdx.x & 7;
    const int tid = threadIdx.x, lane = tid & 63, w = tid >> 6;   // w: 0..7
    const float* pp_b = pp + (size_t)b*16*HD;
    if (tid < 256){
        int head = tid >> 7, m = tid & 127;
        int col = head ? (134 + m) : m;
        float v = bh[col];
        #pragma unroll
        for (int ks = 0; ks < 16; ++ks) v += pp_b[ks*HD + col];
        kh[tid] = tanhf(v);
    }
    __syncthreads();
    float2 kr  = reinterpret_cast<const float2*>(kh)[lane];
    float2 kw2 = reinterpret_cast<const float2*>(kh + 128)[lane];
    #pragma unroll 2
    for (int i = 0; i < 8; ++i){
        int n = nq*64 + w*8 + i;
        const __half* mrow = Mem + ((size_t)b*N + n)*M;
        __half2 mh = *reinterpret_cast<const __half2*>(mrow + lane*2);
        float2 mv = __half22float2(mh);
        float s2 = mv.x*mv.x + mv.y*mv.y;
        float dr = mv.x*kr.x + mv.y*kr.y;
        float dw = mv.x*kw2.x + mv.y*kw2.y;
        #pragma unroll
        for (int off = 32; off; off >>= 1){
            s2 += __shfl_xor(s2, off);
            dr += __shfl_xor(dr, off);
            dw += __shfl_xor(dw, off);
        }
        if (lane == 0){
            mnorm[b*N + n] = sqrtf(s2);
            dots[(b*2+0)*N + n] = dr;
            dots[(b*2+1)*N + n] = dw;
        }
    }
}

// group-local (512-thread) reductions; both halves call in lockstep
__device__ __forceinline__ float blk_sum8g(float v, volatile float* red8, int lane, int wgi){
    #pragma unroll
    for (int off = 32; off; off >>= 1) v += __shfl_xor(v, off);
    if (lane == 0) red8[wgi] = v;
    __syncthreads();
    float r = red8[0]+red8[1]+red8[2]+red8[3]+red8[4]+red8[5]+red8[6]+red8[7];
    __syncthreads();
    return r;
}
__device__ __forceinline__ float blk_max8g(float v, volatile float* red8, int lane, int wgi){
    #pragma unroll
    for (int off = 32; off; off >>= 1) v = fmaxf(v, __shfl_xor(v, off));
    if (lane == 0) red8[wgi] = v;
    __syncthreads();
    float r = fmaxf(fmaxf(fmaxf(red8[0],red8[1]),fmaxf(red8[2],red8[3])),
                    fmaxf(fmaxf(red8[4],red8[5]),fmaxf(red8[6],red8[7])));
    __syncthreads();
    return r;
}

// ---------- K4: params finalize + redundant addressing (heads parallel) + Mem update + reads ----------
// grid 256 (b,nq) x 1024
__global__ __launch_bounds__(1024) void k4_addr(
    const float* __restrict__ pp, const float* __restrict__ bh,
    const float* __restrict__ mnorm, const float* __restrict__ dots,
    float* __restrict__ wst, __half* __restrict__ Mem, float* __restrict__ rp, int t)
{
    __shared__ float kh[256];
    __shared__ float sc[12];
    __shared__ float eal[256];
    __shared__ float wfin[1024];
    __shared__ float wgbuf[1024];
    __shared__ float red8[2][8];
    __shared__ float racc_s[1024];
    const int b = blockIdx.x >> 2, nq = blockIdx.x & 3;
    const int tid = threadIdx.x, lane = tid & 63;
    const float* pp_b = pp + (size_t)b*16*HD;

    // phase A: finalize khat / scal / erase,add from contiguous pp slice
    if (tid < 256){
        int head = tid >> 7, m = tid & 127;
        int col = head ? (134 + m) : m;
        float v = bh[col];
        #pragma unroll
        for (int ks = 0; ks < 16; ++ks) v += pp_b[ks*HD + col];
        kh[tid] = tanhf(v);
    } else if (tid < 268){
        int i = tid - 256;                    // 0..11
        int ii = (i < 6) ? i : i - 6;
        int col = (i < 6) ? (128 + ii) : (262 + ii);
        float v = bh[col];
        #pragma unroll
        for (int ks = 0; ks < 16; ++ks) v += pp_b[ks*HD + col];
        sc[i] = (ii==0) ? softplusf(v) : (ii==1) ? sigmoidf(v) : (ii==5) ? 1.f+softplusf(v) : v;
    } else if (tid < 524){
        int j = tid - 268;                    // 0..255
        int col = 268 + j;
        float v = bh[col];
        #pragma unroll
        for (int ks = 0; ks < 16; ++ks) v += pp_b[ks*HD + col];
        eal[j] = (j < 128) ? sigmoidf(v) : tanhf(v);
    }
    __syncthreads();

    // phase B: addressing, both heads in parallel 512-thread halves (redundant across siblings)
    {
        const int g = tid >> 9;          // head
        const int n = tid & 511;
        const int wgi = (tid >> 6) & 7;
        float* wgl = wgbuf + g*512;
        volatile float* r8 = red8[g];

        float kv = (n < 128) ? kh[g*128 + n] : 0.f;
        float knm = sqrtf(blk_sum8g(kv*kv, r8, lane, wgi));
        float beta = sc[g*6+0], gg = sc[g*6+1], gamma = sc[g*6+5];
        float s0r = sc[g*6+2], s1r = sc[g*6+3], s2r = sc[g*6+4];
        float smx = fmaxf(s0r, fmaxf(s1r, s2r));
        float e0 = expf(s0r-smx), e1 = expf(s1r-smx), e2 = expf(s2r-smx);
        float esum = e0+e1+e2;
        float s0 = e0/esum, s1 = e1/esum, s2 = e2/esum;

        float sim = dots[(b*2+g)*N + n] / (mnorm[b*N + n]*knm + EPS);
        float aa = beta * sim;
        float amax = blk_max8g(aa, r8, lane, wgi);
        float ev = expf(aa - amax);
        float wc = ev / blk_sum8g(ev, r8, lane, wgi);

        const float* wpr = wst + ((size_t)((t&1)*2 + g))*(B*N);
        float*       wnx = wst + ((size_t)(((t+1)&1)*2 + g))*(B*N);
        float wprev = wpr[b*N + n];
        float wgv = gg*wc + (1.f - gg)*wprev;
        wgl[n] = wgv; __syncthreads();
        float wsv = s0*wgl[(n+1)&511] + s1*wgv + s2*wgl[(n-1)&511];
        float wp2 = powf(wsv + EPS, gamma);
        float wsum = blk_sum8g(wp2, r8, lane, wgi);
        float wv = wp2 / wsum;
        wfin[g*512 + n] = wv;
        if (nq == 0) wnx[b*N + n] = wv;
        __syncthreads();
    }

    // phase C: read (old Mem) + erase/add on own (b,nq) slice of 128 rows
    {
        const int m = tid & 127, ns = tid >> 7;   // 8 row-groups
        const float e  = eal[m];
        const float ad = eal[128 + m];
        float racc = 0.f;
        #pragma unroll 4
        for (int i2 = 0; i2 < 16; ++i2){
            int nn = nq*128 + i2*8 + ns;
            size_t idx = ((size_t)b*N + nn)*M + m;
            float v = __half2float(Mem[idx]);
            float wr = wfin[nn], ww = wfin[512 + nn];
            racc += wr*v;
            Mem[idx] = __float2half_rn(v*(1.f - ww*e) + ww*ad);
        }
        racc_s[tid] = racc;
        __syncthreads();
        if (tid < 128){
            float s = 0.f;
            #pragma unroll
            for (int g2 = 0; g2 < 8; ++g2) s += racc_s[g2*128 + tid];
            rp[(size_t)nq*8192 + tid*64 + b] = s;
        }
    }
}

// ---------- k_fin: last step's reads -> hist. grid 32 x 256 ----------
__global__ __launch_bounds__(256) void k_fin(const float* __restrict__ rp, float* __restrict__ hist){
    int e = blockIdx.x*256 + threadIdx.x;
    float s = rp[e] + rp[8192+e] + rp[16384+e] + rp[24576+e];
    hist[((size_t)31*K5K + 1024 + (e>>6))*64 + (e&63)] = s;
}

// ---------- K5: out = sigmoid([h, reads]·Wo + bo), all 32 write steps. grid 256 x 512 ----------
__global__ __launch_bounds__(512) void k5_out(
    const float* __restrict__ hist, const float* __restrict__ Wo, const float* __restrict__ bo,
    float* __restrict__ out)
{
    __shared__ float smem[16384];
    const int tid = threadIdx.x, lane = tid & 63, w = tid >> 6;
    const int l = blockIdx.x >> 3, jg = blockIdx.x & 7;
    const int j0 = jg*32;
    float acc[32];
    #pragma unroll
    for (int i = 0; i < 32; ++i) acc[i] = 0.f;
    const int k0 = w*144;
    #pragma unroll 2
    for (int kk = 0; kk < 144; ++kk){
        int k = k0 + kk;
        float a = hist[((size_t)l*K5K + k)*64 + lane];
        const float* wrow = Wo + (size_t)k*D + j0;
        #pragma unroll
        for (int qq = 0; qq < 8; ++qq){
            float4 wv = *reinterpret_cast<const float4*>(wrow + qq*4);
            acc[qq*4+0] += a*wv.x; acc[qq*4+1] += a*wv.y;
            acc[qq*4+2] += a*wv.z; acc[qq*4+3] += a*wv.w;
        }
    }
    __syncthreads();
    #pragma unroll
    for (int c = 0; c < 32; ++c) smem[(w*32 + c)*64 + lane] = acc[c];
    __syncthreads();
    {
        const int b2 = tid >> 3, jq = tid & 7;
        float4 ov;
        float* po = (float*)&ov;
        #pragma unroll
        for (int i = 0; i < 4; ++i){
            int c = jq*4 + i;
            float s = bo[j0 + c];
            #pragma unroll
            for (int ks = 0; ks < 8; ++ks) s += smem[(ks*32 + c)*64 + b2];
            po[i] = sigmoidf(s);
        }
        *reinterpret_cast<float4*>(out + ((size_t)b2*L_WRITE + l)*D + j0 + jq*4) = ov;
    }
}

extern "C" void kernel_launch(void* const* d_in, const int* in_sizes, int n_in,
                              void* d_out, int out_size, void* d_ws, size_t ws_size,
                              hipStream_t stream)
{
    const float* x   = (const float*)d_in[0];
    const float* Wl  = (const float*)d_in[1];
    const float* Ul  = (const float*)d_in[2];
    const float* bl  = (const float*)d_in[3];
    const float* Wh  = (const float*)d_in[4];
    const float* bh  = (const float*)d_in[5];
    const float* Wo  = (const float*)d_in[6];
    const float* bo  = (const float*)d_in[7];
    float* out = (float*)d_out;

    float* ws = (float*)d_ws;
    float* xT    = ws; ws += (size_t)T_READ*D*64;       // 8.4 MB
    __half* Wreh = (__half*)ws; ws += (size_t)1408*4096/2;   // 11.5 MB
    __half* Whh  = (__half*)ws; ws += (size_t)1024*HD/2 + 64;
    float* ht    = ws; ws += (size_t)R*64;
    float* c_t   = ws; ws += (size_t)R*64;
    float* pp    = ws; ws += (size_t)B*16*HD;           // 2.1 MB  [b][ks][col]
    float* mnorm = ws; ws += (size_t)B*N;
    float* dots  = ws; ws += (size_t)B*2*N;
    float* wst   = ws; ws += (size_t)4*B*N;             // parity x head
    __half* Mem  = (__half*)ws; ws += BNM/2;            // 8.4 MB fp16
    float* rp    = ws; ws += (size_t)4*128*64;
    float* hist  = ws; ws += (size_t)L_WRITE*K5K*64;    // 9.4 MB

    hipLaunchKernelGGL(kx_transpose, dim3(T_READ*4), dim3(256), 0, stream, x, xT);
    hipLaunchKernelGGL(kpack_w,      dim3(1408),     dim3(256), 0, stream, Wl, Ul, Wreh);
    hipLaunchKernelGGL(kpack_wh,     dim3(1024),     dim3(256), 0, stream, Wh, Whh);
    hipLaunchKernelGGL(k_init,       dim3(2048),     dim3(256), 0, stream, ht, c_t, rp, wst, Mem);

    for (int t = 0; t < TT; ++t){
        hipLaunchKernelGGL(k1_z,     dim3(256), dim3(1024), 0, stream, xT, Wreh, bl, ht, c_t, rp, hist, t);
        hipLaunchKernelGGL(k2_heads, dim3(524), dim3(256),  0, stream, ht, Whh, pp);
        hipLaunchKernelGGL(k3_dots,  dim3(512), dim3(512),  0, stream, pp, bh, Mem, mnorm, dots);
        hipLaunchKernelGGL(k4_addr,  dim3(256), dim3(1024), 0, stream, pp, bh, mnorm, dots, wst, Mem, rp, t);
    }
    hipLaunchKernelGGL(k_fin,  dim3(32),  dim3(256), 0, stream, rp, hist);
    hipLaunchKernelGGL(k5_out, dim3(256), dim3(512), 0, stream, hist, Wo, bo, out);
}